// Round 14
// baseline (939.346 us; speedup 1.0000x reference)
//
#include <hip/hip_runtime.h>
#include <hip/hip_bf16.h>
#include <cstdint>

typedef unsigned short u16;
typedef __attribute__((ext_vector_type(8))) _Float16 f16x8;
typedef __attribute__((ext_vector_type(4))) float f32x4;
typedef __attribute__((ext_vector_type(8))) unsigned short u16x8;

typedef const __attribute__((address_space(1))) void* gas1p;
typedef __attribute__((address_space(3))) void* las3p;
typedef const __attribute__((address_space(3))) u16* lc16p;

__device__ __forceinline__ void gld_lds16(const void* g, void* l) {
    __builtin_amdgcn_global_load_lds((gas1p)g, (las3p)l, 16, 0, 0);
}

template<int OFF>
__device__ __forceinline__ f16x8 dsr128o(const u16* p) {
    f16x8 r;
    asm volatile("ds_read_b128 %0, %1 offset:%2" : "=v"(r) : "v"((lc16p)p), "i"(OFF));
    return r;
}

__device__ __forceinline__ u16 f2h(float f) {
    _Float16 h = (_Float16)f;
    return __builtin_bit_cast(u16, h);
}

// ---------------- prep: x fp32 -> fp16 (linear, layer-1 LDS path) ----------------
__global__ void cvt_x_kernel(const float4* __restrict__ x, u16* __restrict__ xb) {
    size_t i = (size_t)blockIdx.x * blockDim.x + threadIdx.x;
    float4 a = x[2 * i];
    float4 b = x[2 * i + 1];
    u16x8 o;
    o[0] = f2h(a.x); o[1] = f2h(a.y); o[2] = f2h(a.z); o[3] = f2h(a.w);
    o[4] = f2h(b.x); o[5] = f2h(b.y); o[6] = f2h(b.z); o[7] = f2h(b.w);
    *(u16x8*)&xb[i * 8] = o;
}

// ---------------- prep: weight norm, all 5 layers in 2 launches ----------------
struct WnDesc {
    const float* v; const float* g; u16* wT; float* partial;
    int K; int N; int blk0;
};
struct WnPack { WnDesc d[5]; int nlayer; };

__global__ void wn_partial_all(WnPack p) {
    int b = blockIdx.x;
    int l = 0;
    while (l + 1 < p.nlayer && b >= p.d[l + 1].blk0) l++;
    const WnDesc& d = p.d[l];
    int lb = b - d.blk0;
    int nbx = d.N >> 6;
    int bx = lb % nbx, seg = lb / nbx;

    int lane = threadIdx.x & 63;
    int tr = threadIdx.x >> 6;
    int n = bx * 64 + lane;
    int kseg = d.K >> 3;
    int kbeg = seg * kseg;
    float s = 0.f;
    for (int k = kbeg + tr; k < kbeg + kseg; k += 4) {
        float x = d.v[(size_t)k * d.N + n];
        s += x * x;
    }
    __shared__ float red[4][64];
    red[tr][lane] = s;
    __syncthreads();
    if (tr == 0)
        d.partial[seg * d.N + n] = red[0][lane] + red[1][lane] + red[2][lane] + red[3][lane];
}

__global__ void wn_write_all(WnPack p) {
    int b = blockIdx.x;
    int l = 0;
    while (l + 1 < p.nlayer && b >= p.d[l + 1].blk0) l++;
    const WnDesc& d = p.d[l];
    int lb = b - d.blk0;
    int nbx = d.N >> 6;
    int bx = lb % nbx, seg = lb / nbx;

    int lane = threadIdx.x & 63;
    int tr = threadIdx.x >> 6;
    int n = bx * 64 + lane;
    float s = 0.f;
#pragma unroll
    for (int i = 0; i < 8; i++) s += d.partial[i * d.N + n];
    float sc = d.g[n] / sqrtf(s);

    int kseg = d.K >> 3;
    int kbeg = seg * kseg;
    for (int k = kbeg + tr; k < kbeg + kseg; k += 4)
        d.wT[(size_t)n * d.K + k] = f2h(d.v[(size_t)k * d.N + n] * sc);
}

// ---------------- GEMM v14: 64x256 tile, 4 waves, B-via-LDS, A options --------
// ADIR=1: A read DIRECTLY from global in MFMA-blocked layout [K/8][M][8]
//   (element (m,k) at ((k>>3)*M + m)*8 + (k&7)) -- per-frag load is 4x256B
//   contiguous chunks, L1/L2/L3-hot. No A in LDS, no A barrier coupling.
// ADIR=0 (layer 1): A staged via LDS from linear [M][K] (control path).
// OUTBLK=1: softplus + write blocked layout (feeds next ADIR layer).
// OUTBLK=0: plain f32 row-major (final output).
// B: staged 16KB/K-step, XOR swizzle slot^=((row>>1)&3) (2-way = free),
//    inverse pre-applied on global source (rule #21).
// Ledger (ADIR): iter t: dsr B(t); stB(t+1); lgkm(0); MFMA (compiler forces
//   a(t), spares stB(t+1)); aload(t+1); VMC(4) forces stB(t+1), spares a(t+1);
//   BAR -> cross-wave B(t+1) complete before any wave reads it.
template<int N, int K, bool ADIR, bool OUTBLK>
__global__ __launch_bounds__(256, 4) void gemm_v14(
    const u16* __restrict__ A, const u16* __restrict__ Bt,
    u16* __restrict__ Co, float* __restrict__ Cf)
{
    constexpr int M = 65536;
    constexpr int NT = K / 32;
    constexpr int NTN = N / 256;
    constexpr int NWG = (M / 64) * NTN;
    constexpr int LDSZ = 2 * 8192 + (ADIR ? 0 : 2 * 2048);

    __shared__ u16 lds[LDSZ];

    const int bid = blockIdx.x;
    const int wk = (bid & 7) * (NWG >> 3) + (bid >> 3);   // bijective: NWG%8==0
    const int tm = wk / NTN, tn = wk % NTN;
    const long m0 = (long)tm * 64;
    const int n0 = tn * 256;

    const int tid = threadIdx.x;
    const int lane = tid & 63;
    const int wid = tid >> 6;       // 4 waves, wn = wid*64
    const int wn = wid * 64;

    // ---- B staging: 4 gld_lds/thread; inverse-swizzled source slot ----
    const int rB = tid >> 2;                               // row 0..63 (+64c)
    const int gslot = (tid & 3) ^ ((rB >> 1) & 3);
    const u16* Bsrc = Bt + (size_t)(n0 + rB) * K + gslot * 8;
    auto stB = [&](int buf, int t) {
#pragma unroll
        for (int c = 0; c < 4; c++)
            gld_lds16(Bsrc + (size_t)(64 * c) * K + (size_t)t * 32,
                      &lds[buf * 8192 + c * 2048 + tid * 8]);
    };

    // ---- B fragment read base (swizzled) ----
    const int lrow = lane & 15;
    const int koct = lane >> 4;
    const int swz = (koct ^ ((lrow >> 1) & 3)) * 8;
    const int boffL = lrow * 32 + swz;

    // ---- A: direct-blocked OR LDS-staged ----
    const u16* pA;
    const u16* Asrc = nullptr;
    int aoffL = 0;
    if (ADIR) {
        // pl = ((lane>>4)*M + m0 + (lane&15)) * 8 ; advance 4*M*8 per K-step
        pA = A + ((size_t)koct * M + m0 + lrow) * 8;
    } else {
        const int rA = tid >> 2;
        Asrc = A + (m0 + rA) * (size_t)K + gslot * 8;
        aoffL = lrow * 32 + swz;
        pA = nullptr;
    }
    auto stA = [&](int buf, int t) {   // !ADIR only: 1 gld_lds/thread
        gld_lds16(Asrc + (size_t)t * 32, &lds[16384 + buf * 2048 + tid * 8]);
    };

    f32x4 acc[4][4] = {};
    f16x8 a[4], b[4];

    auto BAR = [&]() { __builtin_amdgcn_s_barrier(); };
#define LGKM0 { asm volatile("s_waitcnt lgkmcnt(0)"); __builtin_amdgcn_sched_barrier(0); }
#define VMC(n) { asm volatile("s_waitcnt vmcnt(" #n ")"); __builtin_amdgcn_sched_barrier(0); }

    auto aload = [&](int t) {          // ADIR: 4 coalesced f16x8 loads
        const u16* p = pA + (size_t)t * (4 * (size_t)M * 8);
#pragma unroll
        for (int fi = 0; fi < 4; fi++)
            a[fi] = *(const f16x8*)(p + fi * 128);
    };

    // ---- prologue ----
    stB(0, 0);
    if (ADIR) {
        aload(0);
        VMC(4);          // forces stB(0); a(0) stays in flight
    } else {
        stA(0, 0);
        VMC(0);
    }
    BAR();

    // ---- main loop ----
    for (int t = 0; t < NT; t++) {
        const int cur = t & 1, nxt = cur ^ 1;
        const bool more = (t + 1 < NT);

        const u16* pB = &lds[cur * 8192 + wn * 32 + boffL];
        b[0] = dsr128o<0>(pB);    b[1] = dsr128o<1024>(pB);
        b[2] = dsr128o<2048>(pB); b[3] = dsr128o<3072>(pB);
        if (!ADIR) {
            const u16* pAl = &lds[16384 + cur * 2048 + aoffL];
            a[0] = dsr128o<0>(pAl);    a[1] = dsr128o<1024>(pAl);
            a[2] = dsr128o<2048>(pAl); a[3] = dsr128o<3072>(pAl);
        }
        if (more) { stB(nxt, t + 1); if (!ADIR) stA(nxt, t + 1); }
        LGKM0;

        __builtin_amdgcn_s_setprio(1);
#pragma unroll
        for (int fi = 0; fi < 4; fi++)
#pragma unroll
            for (int fj = 0; fj < 4; fj++)
                acc[fi][fj] = __builtin_amdgcn_mfma_f32_16x16x32_f16(a[fi], b[fj], acc[fi][fj], 0, 0, 0);
        __builtin_amdgcn_s_setprio(0);

        if (more) {
            if (ADIR) {
                aload(t + 1);
                VMC(4);      // forces stB(t+1); spares a(t+1)
            } else {
                VMC(0);
            }
            BAR();
        }
    }
#undef LGKM0
#undef VMC

    // ---- epilogue: C col = lane&15, row = (lane>>4)*4 + reg ----
    const long crow0 = m0 + ((lane >> 4) << 2);
    const int ccol0 = n0 + wn + (lane & 15);
#pragma unroll
    for (int fi = 0; fi < 4; fi++) {
#pragma unroll
        for (int r = 0; r < 4; r++) {
            const long m = crow0 + fi * 16 + r;
#pragma unroll
            for (int fj = 0; fj < 4; fj++) {
                float v = acc[fi][fj][r];
                if (OUTBLK) {
                    v = fmaxf(v, 0.f) + __logf(1.f + __expf(-fabsf(v)));
                    const int n = ccol0 + fj * 16;
                    Co[((size_t)(n >> 3) * M + m) * 8 + (n & 7)] = f2h(v);
                } else {
                    Cf[(size_t)m * N + ccol0 + fj * 16] = v;
                }
            }
        }
    }
}

// ---------------- launch ----------------
extern "C" void kernel_launch(void* const* d_in, const int* in_sizes, int n_in,
                              void* d_out, int out_size, void* d_ws, size_t ws_size,
                              hipStream_t stream) {
    const float* x  = (const float*)d_in[0];
    const float* v1 = (const float*)d_in[1];
    const float* g1 = (const float*)d_in[2];
    const float* v2 = (const float*)d_in[3];
    const float* g2 = (const float*)d_in[4];
    const float* v3 = (const float*)d_in[5];
    const float* g3 = (const float*)d_in[6];
    const float* v4 = (const float*)d_in[7];
    const float* g4 = (const float*)d_in[8];
    const float* v5 = (const float*)d_in[9];
    const float* g5 = (const float*)d_in[10];
    float* out = (float*)d_out;

    const int M = 65536;
    char* ws = (char*)d_ws;
    u16* bufA = (u16*)(ws);                          // 128 MB (blocked activ.)
    u16* bufB = (u16*)(ws + 0x8000000ULL);           // 128 MB (x linear / blocked)
    u16* w1T  = (u16*)(ws + 0x10000000ULL);
    u16* w2T  = w1T + 1024 * 512;
    u16* w3T  = w2T + 1024 * 1024;
    u16* w4T  = w3T + 1024 * 1024;
    u16* w5T  = w4T + 1024 * 1024;
    float* part = (float*)(ws + 0x10800000ULL);      // 5 x 8 x 1024 f32

    cvt_x_kernel<<<(M * 512) / (256 * 8), 256, 0, stream>>>((const float4*)x, bufB);

    WnPack pk;
    int cum = 0;
    auto mk = [&](int i, const float* v, const float* g, u16* wT, int K, int N) {
        pk.d[i] = WnDesc{v, g, wT, part + i * 8 * 1024, K, N, cum};
        cum += (N / 64) * 8;
    };
    mk(0, v1, g1, w1T, 512, 1024);
    mk(1, v2, g2, w2T, 1024, 1024);
    mk(2, v3, g3, w3T, 1024, 1024);
    mk(3, v4, g4, w4T, 1024, 1024);
    mk(4, v5, g5, w5T, 1024, 512);
    pk.nlayer = 5;

    wn_partial_all<<<cum, 256, 0, stream>>>(pk);
    wn_write_all<<<cum, 256, 0, stream>>>(pk);

    // L1: LDS-A (linear x) -> blocked out ; L2-4: direct-A -> blocked out ;
    // L5: direct-A -> plain f32 out.
    gemm_v14<1024, 512,  false, true ><<<4096, 256, 0, stream>>>(bufB, w1T, bufA, nullptr);
    gemm_v14<1024, 1024, true,  true ><<<4096, 256, 0, stream>>>(bufA, w2T, bufB, nullptr);
    gemm_v14<1024, 1024, true,  true ><<<4096, 256, 0, stream>>>(bufB, w3T, bufA, nullptr);
    gemm_v14<1024, 1024, true,  true ><<<4096, 256, 0, stream>>>(bufA, w4T, bufB, nullptr);
    gemm_v14<512,  1024, true,  false><<<2048, 256, 0, stream>>>(bufB, w5T, nullptr, out);

    (void)in_sizes; (void)n_in; (void)out_size; (void)ws_size;
}